// Round 1
// baseline (389.121 us; speedup 1.0000x reference)
//
#include <hip/hip_runtime.h>

#define EPS 1e-6f

constexpr int KNB = 32;            // K neighbors
constexpr int NFG = 4;
constexpr int NH  = 16;
constexpr int NFO = 32;
constexpr int FH  = NFG * NH;      // 64
constexpr int ACN = KNB * FH;      // 2048 ac elems per row
constexpr int ON  = NFO * NH;      // 512 output elems per row
constexpr int KN  = KNB * NH;      // 512 attn elems per row

__global__ __launch_bounds__(256)
void attn_fused(const float* __restrict__ beta,
                const float* __restrict__ sa,
                const float* __restrict__ ac,
                const float* __restrict__ no,
                const float* __restrict__ gw,
                float* __restrict__ out,       // [BL, 512]
                float* __restrict__ attn_out)  // [BL, 512]
{
    const int bl  = blockIdx.x;
    const int tid = threadIdx.x;

    __shared__ float s_ac[ACN];        // gated ac, [k*64 + f*16 + h]
    __shared__ float s_attn[KN];       // normalized attn, [k*16 + h]
    __shared__ float s_gw[KNB * NFG];  // [k*4 + f]
    __shared__ float s_bg[FH];         // beta + eps
    __shared__ float s_red[256];
    __shared__ float s_m[NH];
    __shared__ float s_d[NH];

    const size_t blz = (size_t)bl;
    const float* acp = ac + blz * ACN;
    const float* nop = no + blz * (size_t)(KNB * ON);
    const float* gwp = gw + blz * (KNB * NFG);

    if (tid < FH) s_bg[tid] = beta[blz * FH + tid] + EPS;
    if (tid < KNB * NFG) s_gw[tid] = gwp[tid];
    __syncthreads();

    const int h = tid & 15;

    // ---- load + gate ac; h is constant per thread (256 % 16 == 0) ----
    float lmax = -INFINITY;
    #pragma unroll
    for (int j = 0; j < 8; ++j) {
        const int idx = tid + j * 256;
        const int k   = idx >> 6;
        const int fh  = idx & 63;
        float v = acp[idx];
        if (k == 0) v += sa[blz * FH + fh];
        v *= s_bg[fh];
        s_ac[idx] = v;
        lmax = fmaxf(lmax, v);
    }

    // ---- per-h max via stride-16-preserving tree reduce ----
    s_red[tid] = lmax;
    __syncthreads();
    if (tid < 128) s_red[tid] = fmaxf(s_red[tid], s_red[tid + 128]);
    __syncthreads();
    if (tid < 64)  s_red[tid] = fmaxf(s_red[tid], s_red[tid + 64]);
    __syncthreads();
    if (tid < 32)  s_red[tid] = fmaxf(s_red[tid], s_red[tid + 32]);
    __syncthreads();
    if (tid < 16)  s_m[tid]   = fmaxf(s_red[tid], s_red[tid + 16]);
    __syncthreads();

    // ---- exp, gw-weight, sum over f: 2 (k,h) pairs per thread ----
    const float m = s_m[h];
    const int k0 = tid >> 4;
    const int k1 = k0 + 16;
    float a0 = 0.f, a1 = 0.f;
    #pragma unroll
    for (int f = 0; f < NFG; ++f) {
        a0 += expf(s_ac[k0 * 64 + f * 16 + h] - m) * s_gw[k0 * 4 + f];
        a1 += expf(s_ac[k1 * 64 + f * 16 + h] - m) * s_gw[k1 * 4 + f];
    }

    // ---- per-h abs-sum over k (same stride-16 tree) ----
    __syncthreads();
    s_red[tid] = fabsf(a0) + fabsf(a1);
    __syncthreads();
    if (tid < 128) s_red[tid] += s_red[tid + 128];
    __syncthreads();
    if (tid < 64)  s_red[tid] += s_red[tid + 64];
    __syncthreads();
    if (tid < 32)  s_red[tid] += s_red[tid + 32];
    __syncthreads();
    if (tid < 16)  s_d[tid]   = s_red[tid] + s_red[tid + 16];
    __syncthreads();

    const float den = s_d[h] + EPS;
    const float n0 = a0 / den;
    const float n1 = a1 / den;
    s_attn[tid]        = n0;            // position k0*16+h == tid
    s_attn[tid + 256]  = n1;            // position k1*16+h == tid+256
    attn_out[blz * KN + tid]       = n0;
    attn_out[blz * KN + tid + 256] = n1;
    __syncthreads();

    // ---- einsum over k: out[f,h] = sum_k no[k, f*16+h] * attn[k,h] ----
    const int i2 = tid * 2;          // even => h0 even, h1 = h0+1
    const int h0 = i2 & 15;
    float accx = 0.f, accy = 0.f;
    #pragma unroll
    for (int k = 0; k < KNB; ++k) {
        const float2 v = *reinterpret_cast<const float2*>(nop + k * ON + i2);
        accx += v.x * s_attn[k * NH + h0];
        accy += v.y * s_attn[k * NH + h0 + 1];
    }
    float2 r; r.x = accx; r.y = accy;
    *reinterpret_cast<float2*>(out + blz * ON + i2) = r;
}

extern "C" void kernel_launch(void* const* d_in, const int* in_sizes, int n_in,
                              void* d_out, int out_size, void* d_ws, size_t ws_size,
                              hipStream_t stream) {
    const float* beta = (const float*)d_in[0];
    const float* sa   = (const float*)d_in[1];
    const float* ac   = (const float*)d_in[2];
    const float* no   = (const float*)d_in[3];
    const float* gw   = (const float*)d_in[4];

    const int BL = in_sizes[0] / FH;   // B*L = 4096
    float* out      = (float*)d_out;
    float* attn_out = out + (size_t)BL * ON;

    attn_fused<<<BL, 256, 0, stream>>>(beta, sa, ac, no, gw, out, attn_out);
}

// Round 2
// 387.203 us; speedup vs baseline: 1.0050x; 1.0050x over previous
//
#include <hip/hip_runtime.h>

#define EPS 1e-6f

constexpr int KNB = 32;            // K neighbors
constexpr int NFG = 4;
constexpr int NH  = 16;
constexpr int NFO = 32;
constexpr int FH  = NFG * NH;      // 64
constexpr int ACN = KNB * FH;      // 2048 ac elems per row
constexpr int ON  = NFO * NH;      // 512 output elems per row
constexpr int KN  = KNB * NH;      // 512 attn elems per row

__global__ __launch_bounds__(256, 4)
void attn_fused(const float* __restrict__ beta,
                const float* __restrict__ sa,
                const float* __restrict__ ac,
                const float* __restrict__ no,
                const float* __restrict__ gw,
                float* __restrict__ out,       // [BL, 512]
                float* __restrict__ attn_out)  // [BL, 512]
{
    const int bl   = blockIdx.x;
    const int tid  = threadIdx.x;
    const int lane = tid & 63;
    const int wv   = tid >> 6;      // wave id 0..3

    __shared__ float s_ac[ACN];        // gated ac, [k*64 + f*16 + h]
    __shared__ float s_attn[KN];       // normalized attn, [k*16 + h]
    __shared__ float s_gw[KNB * NFG];  // [k*4 + f]
    __shared__ float s_bg[FH];         // beta + eps
    __shared__ float s_wm[4 * NH];     // per-wave per-h max
    __shared__ float s_wd[4 * NH];     // per-wave per-h abs-sum
    __shared__ float s_part[ON];       // odd-k einsum partials

    const size_t blz = (size_t)bl;
    const float* acp = ac + blz * ACN;
    const float* nop = no + blz * (size_t)(KNB * ON);

    if (tid < FH)        s_bg[tid] = beta[blz * FH + tid] + EPS;
    if (tid < KNB * NFG) s_gw[tid] = gw[blz * (KNB * NFG) + tid];
    __syncthreads();

    const int h = tid & 15;

    // ---- load + gate ac; h-class is constant per thread (256 % 16 == 0) ----
    float lmax = -INFINITY;
    #pragma unroll
    for (int j = 0; j < 8; ++j) {
        const int idx = tid + j * 256;
        float v = acp[idx];
        if (j == 0 && tid < FH) v += sa[blz * FH + tid];  // k==0 slot
        v *= s_bg[idx & 63];
        s_ac[idx] = v;
        lmax = fmaxf(lmax, v);
    }

    // ---- per-h max: intra-wave shuffle, one barrier cross-wave ----
    lmax = fmaxf(lmax, __shfl_xor(lmax, 16, 64));
    lmax = fmaxf(lmax, __shfl_xor(lmax, 32, 64));
    if (lane < 16) s_wm[wv * 16 + lane] = lmax;
    __syncthreads();   // also publishes s_ac
    const float m = fmaxf(fmaxf(s_wm[h], s_wm[16 + h]),
                          fmaxf(s_wm[32 + h], s_wm[48 + h]));

    // ---- exp, gw-weight, sum over f: 2 (k,h) pairs per thread ----
    const int k0 = tid >> 4;        // 0..15
    float a0 = 0.f, a1 = 0.f;
    #pragma unroll
    for (int f = 0; f < NFG; ++f) {
        a0 += __expf(s_ac[k0 * 64 + f * 16 + h] - m)        * s_gw[k0 * 4 + f];
        a1 += __expf(s_ac[(k0 + 16) * 64 + f * 16 + h] - m) * s_gw[(k0 + 16) * 4 + f];
    }

    // ---- per-h abs-sum over k: same shuffle pattern ----
    float ls = fabsf(a0) + fabsf(a1);
    ls += __shfl_xor(ls, 16, 64);
    ls += __shfl_xor(ls, 32, 64);
    if (lane < 16) s_wd[wv * 16 + lane] = ls;
    __syncthreads();
    const float den = s_wd[h] + s_wd[16 + h] + s_wd[32 + h] + s_wd[48 + h] + EPS;

    const float n0 = a0 / den;
    const float n1 = a1 / den;
    s_attn[tid]       = n0;          // k0*16+h == tid
    s_attn[tid + 256] = n1;          // (k0+16)*16+h == tid+256
    attn_out[blz * KN + tid]       = n0;
    attn_out[blz * KN + tid + 256] = n1;
    __syncthreads();

    // ---- einsum over k, float4 streaming: out[p] = sum_k no[k*512+p]*attn[k*16+(p&15)]
    // threads 0..127 handle even k, 128..255 odd k; combine via LDS.
    const int half = tid >> 7;       // 0 or 1
    const int u    = tid & 127;
    const int p    = u * 4;          // output base position (16B aligned)
    const float* basep = nop + half * ON + p;
    float4 acc = make_float4(0.f, 0.f, 0.f, 0.f);
    #pragma unroll 8
    for (int j = 0; j < 16; ++j) {
        const float4 v = *reinterpret_cast<const float4*>(basep + j * 1024);
        const float4 w = *reinterpret_cast<const float4*>(
            &s_attn[(2 * j + half) * 16 + (p & 15)]);
        acc.x += v.x * w.x;
        acc.y += v.y * w.y;
        acc.z += v.z * w.z;
        acc.w += v.w * w.w;
    }
    if (half) {
        *reinterpret_cast<float4*>(&s_part[p]) = acc;
    }
    __syncthreads();
    if (!half) {
        const float4 q = *reinterpret_cast<const float4*>(&s_part[p]);
        acc.x += q.x; acc.y += q.y; acc.z += q.z; acc.w += q.w;
        *reinterpret_cast<float4*>(out + blz * ON + p) = acc;
    }
}

extern "C" void kernel_launch(void* const* d_in, const int* in_sizes, int n_in,
                              void* d_out, int out_size, void* d_ws, size_t ws_size,
                              hipStream_t stream) {
    const float* beta = (const float*)d_in[0];
    const float* sa   = (const float*)d_in[1];
    const float* ac   = (const float*)d_in[2];
    const float* no   = (const float*)d_in[3];
    const float* gw   = (const float*)d_in[4];

    const int BL = in_sizes[0] / FH;   // B*L = 4096
    float* out      = (float*)d_out;
    float* attn_out = out + (size_t)BL * ON;

    attn_fused<<<BL, 256, 0, stream>>>(beta, sa, ac, no, gw, out, attn_out);
}